// Round 1
// baseline (38.623 us; speedup 1.0000x reference)
//
#include <hip/hip_runtime.h>

#define SQ 1024
#define HH 16
#define DK 4
#define EE 64

// Kernel 1: quantum-projection + per-(b,h) attention, flash-style.
// grid = B*H*(S/256) = 256 blocks, 256 threads. Each block: one (b,h), one
// 256-row query tile. All 1024 keys staged in LDS (16 KB, float4 each).
__global__ __launch_bounds__(256) void qattn_kernel(
    const float* __restrict__ x, const float* __restrict__ theta,
    float* __restrict__ y) {
  const int tid = threadIdx.x;
  const int tile = blockIdx.x;       // 0..255
  const int qt = tile & 3;           // query tile within (b,h)
  const int bh = tile >> 2;          // 0..63
  const int h = bh & (HH - 1);
  const int b = bh >> 4;

  __shared__ float4 kv[SQ];          // 16 KB of proj keys

  const float4 th = *reinterpret_cast<const float4*>(theta);
  const float4 ct = make_float4(__cosf(th.x), __cosf(th.y),
                                __cosf(th.z), __cosf(th.w));

  // Stage proj keys: x[b, t, h*4 + d] is a contiguous float4 per t.
  const float* xb = x + ((size_t)b * SQ) * EE + h * DK;
#pragma unroll
  for (int k = 0; k < 4; ++k) {
    const int t = tid + k * 256;
    const float4 v = *reinterpret_cast<const float4*>(xb + (size_t)t * EE);
    kv[t] = make_float4(__cosf(v.x) * ct.x, __cosf(v.y) * ct.y,
                        __cosf(v.z) * ct.z, __cosf(v.w) * ct.w);
  }
  __syncthreads();

  const int q = qt * 256 + tid;
  const float4 qv = kv[q];
  float den = 0.f;
  float4 num = make_float4(0.f, 0.f, 0.f, 0.f);
  // |score| <= 2 so plain exp (no running max) is exact-enough softmax.
#pragma unroll 8
  for (int t = 0; t < SQ; ++t) {
    const float4 k = kv[t];  // same address across wave -> LDS broadcast
    const float s = (qv.x * k.x + qv.y * k.y + qv.z * k.z + qv.w * k.w) * 0.5f;
    const float e = __expf(s);
    den += e;
    num.x += e * k.x; num.y += e * k.y; num.z += e * k.z; num.w += e * k.w;
  }
  const float inv = 1.f / den;
  float* yp = y + ((size_t)(b * SQ + q)) * EE + h * DK;
  *reinterpret_cast<float4*>(yp) =
      make_float4(num.x * inv, num.y * inv, num.z * inv, num.w * inv);
}

// Kernel 2: out[t,e] = bias[e] + sum_j y[t,j] * W[e,j]  (4096 x 64 x 64).
// grid = 4096/16 = 256 blocks, 256 threads. W staged transposed in LDS.
__global__ __launch_bounds__(256) void proj_kernel(
    const float* __restrict__ y, const float* __restrict__ W,
    const float* __restrict__ bias, float* __restrict__ out) {
  const int tid = threadIdx.x;
  __shared__ float Wt[EE][EE + 1];   // +1 pad: conflict-free transpose write
  __shared__ float yt[16][EE];

#pragma unroll
  for (int k = 0; k < 16; ++k) {
    const int idx = tid + k * 256;   // linear over W (row-major [e][j])
    Wt[idx & 63][idx >> 6] = W[idx];
  }
  const size_t tok0 = (size_t)blockIdx.x * 16;
#pragma unroll
  for (int k = 0; k < 4; ++k) {
    const int idx = tid + k * 256;   // 16 tokens x 64 = 1024 floats
    yt[idx >> 6][idx & 63] = y[tok0 * EE + idx];
  }
  __syncthreads();

  const int e = tid & 63;            // output column (coalesced stores)
  const int t0 = tid >> 6;           // 0..3; tokens t0, t0+4, t0+8, t0+12
  const float bv = bias[e];
  float acc[4] = {bv, bv, bv, bv};
#pragma unroll
  for (int j = 0; j < EE; ++j) {
    const float w = Wt[j][e];        // consecutive e -> conflict-free
#pragma unroll
    for (int k = 0; k < 4; ++k) acc[k] += yt[t0 + 4 * k][j] * w;  // broadcast
  }
#pragma unroll
  for (int k = 0; k < 4; ++k) {
    out[(tok0 + t0 + 4 * k) * EE + e] = acc[k];
  }
}

extern "C" void kernel_launch(void* const* d_in, const int* in_sizes, int n_in,
                              void* d_out, int out_size, void* d_ws, size_t ws_size,
                              hipStream_t stream) {
  const float* x     = (const float*)d_in[0];
  const float* theta = (const float*)d_in[1];
  const float* W     = (const float*)d_in[2];
  const float* bias  = (const float*)d_in[3];
  float* out = (float*)d_out;
  float* y   = (float*)d_ws;  // [B,S,E] fp32 = 1 MB attention output

  qattn_kernel<<<256, 256, 0, stream>>>(x, theta, y);
  proj_kernel<<<256, 256, 0, stream>>>(y, W, bias, out);
}

// Round 2
// 31.067 us; speedup vs baseline: 1.2432x; 1.2432x over previous
//
#include <hip/hip_runtime.h>

#define SQ 1024
#define HH 16
#define DK 4
#define EE 64

// Kernel 1: quantum-projection + per-(b,h) attention, flash-style.
// grid = B*H*(S/64) = 1024 blocks, 256 threads (4 blocks/CU, 4 waves/SIMD).
// Each block: one (b,h), 64 query rows. Lane = 4*q_local + c where c is a
// 256-key chunk; partial (den,num) reduced over c via shfl_xor(1,2).
__global__ __launch_bounds__(256) void qattn_kernel(
    const float* __restrict__ x, const float* __restrict__ theta,
    float* __restrict__ y) {
  const int tid = threadIdx.x;
  const int qtile = blockIdx.x & 15;   // 16 query tiles of 64
  const int bh = blockIdx.x >> 4;      // 0..63
  const int h = bh & (HH - 1);
  const int b = bh >> 4;

  // Chunk-skewed key store: chunk c starts at c*1028 floats (bank offset 4c)
  // so the 4 distinct per-wave broadcast addresses hit distinct bank quads.
  __shared__ float kvf[4][1028];

  const float4 th = *reinterpret_cast<const float4*>(theta);
  const float4 ct = make_float4(__cosf(th.x), __cosf(th.y),
                                __cosf(th.z), __cosf(th.w));

  // Stage all 1024 proj keys: x[b, t, h*4 + d] is a contiguous float4 per t.
  const float* xb = x + ((size_t)b * SQ) * EE + h * DK;
#pragma unroll
  for (int k = 0; k < 4; ++k) {
    const int t = tid + k * 256;
    const float4 v = *reinterpret_cast<const float4*>(xb + (size_t)t * EE);
    const float4 p = make_float4(__cosf(v.x) * ct.x, __cosf(v.y) * ct.y,
                                 __cosf(v.z) * ct.z, __cosf(v.w) * ct.w);
    *reinterpret_cast<float4*>(&kvf[t >> 8][(t & 255) * 4]) = p;
  }
  __syncthreads();

  const int c = tid & 3;               // key chunk 0..3
  const int ql = tid >> 2;             // query within tile 0..63
  const int q = qtile * 64 + ql;

  const float4 qv =
      *reinterpret_cast<const float4*>(&kvf[q >> 8][(q & 255) * 4]);
  // Fold softmax scale (1/sqrt(4)=0.5) and log2(e) into the query so the
  // inner loop is dot + v_exp_f32 (exp2) + 5 fma. |score|<=2 -> no max sub.
  const float sc = 0.5f * 1.4426950408889634f;
  const float4 qs = make_float4(qv.x * sc, qv.y * sc, qv.z * sc, qv.w * sc);

  float den = 0.f;
  float4 num = make_float4(0.f, 0.f, 0.f, 0.f);
  const float* kc = kvf[c];
#pragma unroll 8
  for (int t = 0; t < 256; ++t) {
    const float4 kk = *reinterpret_cast<const float4*>(&kc[t * 4]);
    const float s = qs.x * kk.x + qs.y * kk.y + qs.z * kk.z + qs.w * kk.w;
    const float e = __builtin_amdgcn_exp2f(s);
    den += e;
    num.x += e * kk.x; num.y += e * kk.y;
    num.z += e * kk.z; num.w += e * kk.w;
  }

  // Reduce the 4 chunk lanes (lane bits 0-1).
  den += __shfl_xor(den, 1); num.x += __shfl_xor(num.x, 1);
  num.y += __shfl_xor(num.y, 1); num.z += __shfl_xor(num.z, 1);
  num.w += __shfl_xor(num.w, 1);
  den += __shfl_xor(den, 2); num.x += __shfl_xor(num.x, 2);
  num.y += __shfl_xor(num.y, 2); num.z += __shfl_xor(num.z, 2);
  num.w += __shfl_xor(num.w, 2);

  if (c == 0) {
    const float inv = 1.f / den;
    float* yp = y + ((size_t)(b * SQ + q)) * EE + h * DK;
    *reinterpret_cast<float4*>(yp) =
        make_float4(num.x * inv, num.y * inv, num.z * inv, num.w * inv);
  }
}

// Kernel 2: out[t,e] = bias[e] + sum_j y[t,j] * W[e,j]  (4096 x 64 x 64).
// grid = 4096/16 = 256 blocks, 256 threads. W staged transposed in LDS.
__global__ __launch_bounds__(256) void proj_kernel(
    const float* __restrict__ y, const float* __restrict__ W,
    const float* __restrict__ bias, float* __restrict__ out) {
  const int tid = threadIdx.x;
  __shared__ float Wt[EE][EE + 1];   // +1 pad: conflict-free transpose write
  __shared__ float yt[16][EE];

#pragma unroll
  for (int k = 0; k < 16; ++k) {
    const int idx = tid + k * 256;   // linear over W (row-major [e][j])
    Wt[idx & 63][idx >> 6] = W[idx];
  }
  const size_t tok0 = (size_t)blockIdx.x * 16;
#pragma unroll
  for (int k = 0; k < 4; ++k) {
    const int idx = tid + k * 256;   // 16 tokens x 64 = 1024 floats
    yt[idx >> 6][idx & 63] = y[tok0 * EE + idx];
  }
  __syncthreads();

  const int e = tid & 63;            // output column (coalesced stores)
  const int t0 = tid >> 6;           // 0..3; tokens t0, t0+4, t0+8, t0+12
  const float bv = bias[e];
  float acc[4] = {bv, bv, bv, bv};
#pragma unroll
  for (int j = 0; j < EE; ++j) {
    const float w = Wt[j][e];        // consecutive e -> conflict-free
#pragma unroll
    for (int k = 0; k < 4; ++k) acc[k] += yt[t0 + 4 * k][j] * w;  // broadcast
  }
#pragma unroll
  for (int k = 0; k < 4; ++k) {
    out[(tok0 + t0 + 4 * k) * EE + e] = acc[k];
  }
}

extern "C" void kernel_launch(void* const* d_in, const int* in_sizes, int n_in,
                              void* d_out, int out_size, void* d_ws, size_t ws_size,
                              hipStream_t stream) {
  const float* x     = (const float*)d_in[0];
  const float* theta = (const float*)d_in[1];
  const float* W     = (const float*)d_in[2];
  const float* bias  = (const float*)d_in[3];
  float* out = (float*)d_out;
  float* y   = (float*)d_ws;  // [B,S,E] fp32 = 1 MB attention output

  qattn_kernel<<<1024, 256, 0, stream>>>(x, theta, y);
  proj_kernel<<<256, 256, 0, stream>>>(y, W, bias, out);
}